// Round 1
// baseline (384.726 us; speedup 1.0000x reference)
//
#include <hip/hip_runtime.h>

#define N_    8192
#define FIN_  256
#define NHID_ 128
#define E_    524288
#define KTOP  32
#define CAP   160    // per-row assembly capacity; Binomial(E,1/N): mean 64, sigma 8 -> +12 sigma
#define HASHSZ 512   // LDS hash slots for dup detection
#define SCB   128    // scatter blocks (each owns E_/SCB edges and a private cell per row)
#define EPB   (E_ / SCB)   // 4096 edges per scatter block -> Poisson(0.5) per (row,block) cell
#define CELL  32     // u16 slots per (row,block) cell = exactly one 64B line: no cross-XCD sharing

typedef unsigned short ushort_t;

// ---- edge counting-sort, ZERO global atomics ----
// Each block histograms its private 4096-edge slice in LDS (intra-CU atomics only)
// and places each edge into its own (row, block) 64B cell. Replaces 512K device-scope
// atomicAdd + cross-XCD line ping-pong (theory: ~250us of the 337us baseline).
__global__ __launch_bounds__(256) void k_scatter(const int* __restrict__ ei,
                                                 ushort_t* __restrict__ ecol2d,
                                                 ushort_t* __restrict__ cnt2d) {
    __shared__ int histo[N_];   // 32 KB
    int t = threadIdx.x;
    int blk = blockIdx.x;

    int4* h4 = (int4*)histo;
#pragma unroll
    for (int i = 0; i < 8; ++i) h4[t + 256 * i] = make_int4(0, 0, 0, 0);
    __syncthreads();

    const int4* rg = (const int4*)ei + blk * (EPB / 4);
    const int4* cg = (const int4*)(ei + E_) + blk * (EPB / 4);
#pragma unroll
    for (int i = 0; i < EPB / 4 / 256; ++i) {   // 4 iterations
        int4 r4 = rg[t + 256 * i];
        int4 c4 = cg[t + 256 * i];
        int p;
        p = atomicAdd(&histo[r4.x], 1); if (p < CELL) ecol2d[(size_t)r4.x * (SCB * CELL) + blk * CELL + p] = (ushort_t)c4.x;
        p = atomicAdd(&histo[r4.y], 1); if (p < CELL) ecol2d[(size_t)r4.y * (SCB * CELL) + blk * CELL + p] = (ushort_t)c4.y;
        p = atomicAdd(&histo[r4.z], 1); if (p < CELL) ecol2d[(size_t)r4.z * (SCB * CELL) + blk * CELL + p] = (ushort_t)c4.z;
        p = atomicAdd(&histo[r4.w], 1); if (p < CELL) ecol2d[(size_t)r4.w * (SCB * CELL) + blk * CELL + p] = (ushort_t)c4.w;
    }
    __syncthreads();

    // transposed counts: block-contiguous -> fully coalesced 16KB store per block
#pragma unroll
    for (int i = 0; i < 32; ++i) {
        int rr = t + 256 * i;
        int c = histo[rr]; if (c > CELL) c = CELL;
        cnt2d[(size_t)blk * N_ + rr] = (ushort_t)c;
    }
}

// ---- h = relu(x @ W1 + b1) + a,b epilogue (scatter removed) ----
// 512 blocks (2/CU): 16 rows/block, thread = 2 rows x 4 cols. 2 waves/SIMD hides
// L1 latency on the 8x-redundant W1 reads.
__global__ __launch_bounds__(256) void k_fused(const float* __restrict__ x,
                                               const float* __restrict__ W1,
                                               const float* __restrict__ b1,
                                               const float* __restrict__ We,
                                               float* __restrict__ h,
                                               float* __restrict__ a,
                                               float* __restrict__ b) {
    __shared__ float xs[16][FIN_];
    int t = threadIdx.x;
    int blk = blockIdx.x;

    int row0 = blk * 16;
    const float4* xg = (const float4*)(x + (size_t)row0 * FIN_);
    float4* xs4 = (float4*)&xs[0][0];
#pragma unroll
    for (int i = 0; i < 4; ++i) xs4[t + 256 * i] = xg[t + 256 * i];
    __syncthreads();

    int rg = t >> 5;
    int jg = t & 31;
    int r0 = 2 * rg, r1 = 2 * rg + 1;
    const float* wp = W1 + jg * 4;
    float4 bb = *(const float4*)(b1 + jg * 4);
    float4 acc0 = bb, acc1 = bb;
    const float* xr0 = xs[r0];
    const float* xr1 = xs[r1];
#pragma unroll 8
    for (int k = 0; k < FIN_; ++k) {
        float4 w = *(const float4*)(wp + (size_t)k * NHID_);
        float x0 = xr0[k], x1 = xr1[k];
        acc0.x = fmaf(x0, w.x, acc0.x);
        acc0.y = fmaf(x0, w.y, acc0.y);
        acc0.z = fmaf(x0, w.z, acc0.z);
        acc0.w = fmaf(x0, w.w, acc0.w);
        acc1.x = fmaf(x1, w.x, acc1.x);
        acc1.y = fmaf(x1, w.y, acc1.y);
        acc1.z = fmaf(x1, w.z, acc1.z);
        acc1.w = fmaf(x1, w.w, acc1.w);
    }
    acc0.x = fmaxf(acc0.x, 0.f); acc0.y = fmaxf(acc0.y, 0.f);
    acc0.z = fmaxf(acc0.z, 0.f); acc0.w = fmaxf(acc0.w, 0.f);
    acc1.x = fmaxf(acc1.x, 0.f); acc1.y = fmaxf(acc1.y, 0.f);
    acc1.z = fmaxf(acc1.z, 0.f); acc1.w = fmaxf(acc1.w, 0.f);
    *(float4*)(h + (size_t)(row0 + r0) * NHID_ + jg * 4) = acc0;
    *(float4*)(h + (size_t)(row0 + r1) * NHID_ + jg * 4) = acc1;

    float4 we1 = *(const float4*)(We + jg * 4);
    float4 we2 = *(const float4*)(We + NHID_ + jg * 4);
    float p0 = acc0.x * we1.x + acc0.y * we1.y + acc0.z * we1.z + acc0.w * we1.w;
    float q0 = acc0.x * we2.x + acc0.y * we2.y + acc0.z * we2.z + acc0.w * we2.w;
    float p1 = acc1.x * we1.x + acc1.y * we1.y + acc1.z * we1.z + acc1.w * we1.w;
    float q1 = acc1.x * we2.x + acc1.y * we2.y + acc1.z * we2.z + acc1.w * we2.w;
#pragma unroll
    for (int o = 16; o > 0; o >>= 1) {
        p0 += __shfl_down(p0, o, 32);
        q0 += __shfl_down(q0, o, 32);
        p1 += __shfl_down(p1, o, 32);
        q1 += __shfl_down(q1, o, 32);
    }
    if (jg == 0) {
        a[row0 + r0] = p0; b[row0 + r0] = q0;
        a[row0 + r1] = p1; b[row0 + r1] = q1;
    }
}

// ---- per-row sparsemax + topK ----
// New: (1) pre-zero the whole output row at kernel start (stores overlap compute;
// intervening __syncthreads drains vmcnt -> WAW-safe sparse overwrite at the end),
// (2) bucket assembly = 128-wide count gather + wave prefix-sum + per-cell copy.
// bitmap/hval/nibble dense pass deleted.
__global__ __launch_bounds__(256) void k_rows(const ushort_t* __restrict__ cnt2d,
                                              const ushort_t* __restrict__ ecol2d,
                                              const float* __restrict__ a,
                                              const float* __restrict__ b,
                                              const float* __restrict__ be,
                                              float* __restrict__ adj) {
    __shared__ float zs[CAP];
    __shared__ int   cols[CAP];
    __shared__ float srt[CAP];
    __shared__ unsigned char dupf[CAP];
    __shared__ unsigned char dupsrt[CAP];
    __shared__ int   hcol[HASHSZ];
    __shared__ int   hidx[HASHSZ];
    __shared__ ushort_t scnt[SCB];
    __shared__ int   sbase[SCB];
    __shared__ int   s_m;
    __shared__ float s_tau, s_thresh;

    int r = blockIdx.x;
    int t = threadIdx.x;

    // stream zeros for the full output row immediately — no dependencies, overlaps
    // everything below; replaces the tail dense write pass.
    {
        float4 z4 = make_float4(0.f, 0.f, 0.f, 0.f);
        float4* row4 = (float4*)(adj + (size_t)r * N_);
#pragma unroll
        for (int k2 = 0; k2 < 8; ++k2) row4[t + 256 * k2] = z4;
    }

    hcol[t] = -1;         hcol[t + 256] = -1;
    hidx[t] = 0x7fffffff; hidx[t + 256] = 0x7fffffff;
    if (t < SCB) scnt[t] = cnt2d[(size_t)t * N_ + r];
    __syncthreads();

    // exclusive prefix over 128 per-block counts (wave 0, two segments)
    if (t < 64) {
        int v0 = scnt[t], v1 = scnt[t + 64];
        int sc0 = v0, sc1 = v1;
#pragma unroll
        for (int o = 1; o < 64; o <<= 1) {
            int u0 = __shfl_up(sc0, o);
            int u1 = __shfl_up(sc1, o);
            if (t >= o) { sc0 += u0; sc1 += u1; }
        }
        int tot0 = __shfl(sc0, 63);
        sc1 += tot0;
        sbase[t] = sc0 - v0;
        sbase[t + 64] = sc1 - v1;
        if (t == 63) s_m = sc1;
    }
    __syncthreads();

    int m = s_m; if (m > CAP) m = CAP;
    float ab = a[r] + be[0];

    // assemble compact cols/zs from the 128 private cells
    if (t < SCB) {
        int base = sbase[t];
        int n = scnt[t];
        const ushort_t* cell = ecol2d + (size_t)r * (SCB * CELL) + t * CELL;
        for (int j = 0; j < n; ++j) {
            int idx = base + j;
            if (idx < CAP) {
                int c = (int)cell[j];
                cols[idx] = c;
                zs[idx] = ab + b[c];
            }
        }
    }
    __syncthreads();

    if (m > 0) {
        // hash insert for duplicate-column detection (first occurrence = min index)
        for (int i = t; i < m; i += 256) {
            int c = cols[i];
            int slot = c & (HASHSZ - 1);
            while (true) {
                int old = atomicCAS(&hcol[slot], -1, c);
                if (old == -1 || old == c) { atomicMin(&hidx[slot], i); break; }
                slot = (slot + 1) & (HASHSZ - 1);
            }
        }
        __syncthreads();

        // O(m^2) rank sort into srt (LDS broadcast reads, m<=160)
        for (int i = t; i < m; i += 256) {
            float zi = zs[i];
            int ci = cols[i];
            int rank = 0;
            for (int jj = 0; jj < m; ++jj) {
                float zj = zs[jj];
                rank += (zj > zi) || (zj == zi && jj < i);
            }
            int slot = ci & (HASHSZ - 1);
            while (hcol[slot] != ci) slot = (slot + 1) & (HASHSZ - 1);
            bool dup = (hidx[slot] != i);
            srt[rank] = zi;
            dupsrt[rank] = dup ? 1 : 0;
            dupf[i] = dup ? 1 : 0;
        }
        __syncthreads();

        // wave 0: sparsemax tau + top-K threshold over sorted values
        if (t < 64) {
            int lane = t;
            float v0 = (lane       < m) ? srt[lane]       : 0.f;
            float v1 = (lane + 64  < m) ? srt[lane + 64]  : 0.f;
            float v2 = (lane + 128 < m) ? srt[lane + 128] : 0.f;
            bool  d0 = (lane       < m) ? (dupsrt[lane]       != 0) : false;
            bool  d1 = (lane + 64  < m) ? (dupsrt[lane + 64]  != 0) : false;
            bool  d2 = (lane + 128 < m) ? (dupsrt[lane + 128] != 0) : false;

            float sc0 = v0, sc1 = v1, sc2 = v2;
#pragma unroll
            for (int o = 1; o < 64; o <<= 1) {
                float u0 = __shfl_up(sc0, o);
                float u1 = __shfl_up(sc1, o);
                float u2 = __shfl_up(sc2, o);
                if (lane >= o) { sc0 += u0; sc1 += u1; sc2 += u2; }
            }
            float tot0 = __shfl(sc0, 63);
            sc1 += tot0;
            float tot1 = __shfl(sc1, 63);
            sc2 += tot1;

            bool k0 = (lane       < m) && (1.f + (float)(lane + 1)   * v0 > sc0);
            bool k1 = (lane + 64  < m) && (1.f + (float)(lane + 65)  * v1 > sc1);
            bool k2 = (lane + 128 < m) && (1.f + (float)(lane + 129) * v2 > sc2);
            unsigned long long kb0 = __ballot(k0), kb1 = __ballot(k1), kb2 = __ballot(k2);
            int kmax;
            if (kb2)      kmax = 128 + 63 - (int)__builtin_clzll(kb2) + 1;
            else if (kb1) kmax = 64  + 63 - (int)__builtin_clzll(kb1) + 1;
            else          kmax =       63 - (int)__builtin_clzll(kb0) + 1;
            int ki = kmax - 1, ks = ki >> 6, kl = ki & 63;
            float csk = (ks == 0) ? __shfl(sc0, kl) : (ks == 1) ? __shfl(sc1, kl) : __shfl(sc2, kl);
            float tau = (csk - 1.f) / (float)kmax;

            unsigned long long dm0 = __ballot(d0), dm1 = __ballot(d1), dm2 = __ballot(d2);
            unsigned long long below = (1ull << lane) - 1ull;
            int pc0 = (int)__popcll(dm0 & below);
            int pc1 = (int)__popcll(dm0) + (int)__popcll(dm1 & below);
            int pc2 = (int)__popcll(dm0) + (int)__popcll(dm1) + (int)__popcll(dm2 & below);
            float cand = 0.f;
            if (lane       < m && !d0 && (lane       - pc0) == KTOP - 1) cand = fmaxf(cand, fmaxf(v0 - tau, 0.f));
            if (lane + 64  < m && !d1 && (lane + 64  - pc1) == KTOP - 1) cand = fmaxf(cand, fmaxf(v1 - tau, 0.f));
            if (lane + 128 < m && !d2 && (lane + 128 - pc2) == KTOP - 1) cand = fmaxf(cand, fmaxf(v2 - tau, 0.f));
#pragma unroll
            for (int o = 32; o > 0; o >>= 1) cand = fmaxf(cand, __shfl_down(cand, o));
            if (lane == 0) { s_tau = tau; s_thresh = cand; }
        }
        __syncthreads();   // also drains the pre-zero stores (vmcnt) -> WAW-safe below
        float tau = s_tau;
        float thresh = s_thresh;

        // sparse overwrite: only surviving entries (duplicate cols have identical
        // values, so first-occurrence-wins matches the dense pass it replaces)
        for (int i = t; i < m; i += 256) {
            if (dupf[i]) continue;
            float s = zs[i] - tau;
            if (s > 0.f && s >= thresh) adj[(size_t)r * N_ + cols[i]] = s;
        }
    }
}

extern "C" void kernel_launch(void* const* d_in, const int* in_sizes, int n_in,
                              void* d_out, int out_size, void* d_ws, size_t ws_size,
                              hipStream_t stream) {
    const float* x  = (const float*)d_in[0];
    const int*   ei = (const int*)d_in[1];
    const float* W1 = (const float*)d_in[2];
    const float* b1 = (const float*)d_in[3];
    const float* We = (const float*)d_in[4];
    const float* be = (const float*)d_in[5];

    float* h_out   = (float*)d_out;                 // (N, NHID)
    float* adj_out = h_out + (size_t)N_ * NHID_;    // (N, N)

    // ws layout: a(32KB) b(32KB) cnt2d(2MB) ecol2d(64MB)  -> ~66MB total
    float*    a      = (float*)d_ws;
    float*    b      = a + N_;
    ushort_t* cnt2d  = (ushort_t*)(b + N_);                 // SCB x N u16
    ushort_t* ecol2d = cnt2d + (size_t)SCB * N_;            // N x SCB x CELL u16

    k_scatter<<<SCB, 256, 0, stream>>>(ei, ecol2d, cnt2d);
    k_fused<<<512, 256, 0, stream>>>(x, W1, b1, We, h_out, a, b);
    k_rows <<<N_, 256, 0, stream>>>(cnt2d, ecol2d, a, b, be, adj_out);
}

// Round 2
// 346.453 us; speedup vs baseline: 1.1105x; 1.1105x over previous
//
#include <hip/hip_runtime.h>

#define N_    8192
#define FIN_  256
#define NHID_ 128
#define E_    524288
#define KTOP  32
#define CAP   160    // bucket capacity per row; Binomial(E,1/N): mean 64, sigma 8 -> 160 = +12 sigma

typedef unsigned short ushort_t;

// ---- fused: edge scatter (device atomics -- measured cheap, R1 alternative regressed)
//      + h = relu(x @ W1 + b1) + a,b epilogue ----
// 512 blocks (2/CU): 16 rows/block, thread = 2 rows x 4 cols. 2 waves/SIMD hides
// L1 latency on the 8x-redundant W1 reads.
__global__ __launch_bounds__(256) void k_fused(const float* __restrict__ x,
                                               const int* __restrict__ ei,
                                               const float* __restrict__ W1,
                                               const float* __restrict__ b1,
                                               const float* __restrict__ We,
                                               float* __restrict__ h,
                                               float* __restrict__ a,
                                               float* __restrict__ b,
                                               int* __restrict__ cnt,
                                               ushort_t* __restrict__ ecol) {
    __shared__ float xs[16][FIN_];
    int t = threadIdx.x;
    int blk = blockIdx.x;

    {
        int4 r4 = ((const int4*)ei)[blk * 256 + t];
        int4 c4 = ((const int4*)(ei + E_))[blk * 256 + t];
        int p;
        p = atomicAdd(&cnt[r4.x], 1); if (p < CAP) ecol[r4.x * CAP + p] = (ushort_t)c4.x;
        p = atomicAdd(&cnt[r4.y], 1); if (p < CAP) ecol[r4.y * CAP + p] = (ushort_t)c4.y;
        p = atomicAdd(&cnt[r4.z], 1); if (p < CAP) ecol[r4.z * CAP + p] = (ushort_t)c4.z;
        p = atomicAdd(&cnt[r4.w], 1); if (p < CAP) ecol[r4.w * CAP + p] = (ushort_t)c4.w;
    }

    int row0 = blk * 16;
    const float4* xg = (const float4*)(x + (size_t)row0 * FIN_);
    float4* xs4 = (float4*)&xs[0][0];
#pragma unroll
    for (int i = 0; i < 4; ++i) xs4[t + 256 * i] = xg[t + 256 * i];
    __syncthreads();

    int rg = t >> 5;
    int jg = t & 31;
    int r0 = 2 * rg, r1 = 2 * rg + 1;
    const float* wp = W1 + jg * 4;
    float4 bb = *(const float4*)(b1 + jg * 4);
    float4 acc0 = bb, acc1 = bb;
    const float* xr0 = xs[r0];
    const float* xr1 = xs[r1];
#pragma unroll 8
    for (int k = 0; k < FIN_; ++k) {
        float4 w = *(const float4*)(wp + (size_t)k * NHID_);
        float x0 = xr0[k], x1 = xr1[k];
        acc0.x = fmaf(x0, w.x, acc0.x);
        acc0.y = fmaf(x0, w.y, acc0.y);
        acc0.z = fmaf(x0, w.z, acc0.z);
        acc0.w = fmaf(x0, w.w, acc0.w);
        acc1.x = fmaf(x1, w.x, acc1.x);
        acc1.y = fmaf(x1, w.y, acc1.y);
        acc1.z = fmaf(x1, w.z, acc1.z);
        acc1.w = fmaf(x1, w.w, acc1.w);
    }
    acc0.x = fmaxf(acc0.x, 0.f); acc0.y = fmaxf(acc0.y, 0.f);
    acc0.z = fmaxf(acc0.z, 0.f); acc0.w = fmaxf(acc0.w, 0.f);
    acc1.x = fmaxf(acc1.x, 0.f); acc1.y = fmaxf(acc1.y, 0.f);
    acc1.w = fmaxf(acc1.w, 0.f); acc1.z = fmaxf(acc1.z, 0.f);
    *(float4*)(h + (size_t)(row0 + r0) * NHID_ + jg * 4) = acc0;
    *(float4*)(h + (size_t)(row0 + r1) * NHID_ + jg * 4) = acc1;

    float4 we1 = *(const float4*)(We + jg * 4);
    float4 we2 = *(const float4*)(We + NHID_ + jg * 4);
    float p0 = acc0.x * we1.x + acc0.y * we1.y + acc0.z * we1.z + acc0.w * we1.w;
    float q0 = acc0.x * we2.x + acc0.y * we2.y + acc0.z * we2.z + acc0.w * we2.w;
    float p1 = acc1.x * we1.x + acc1.y * we1.y + acc1.z * we1.z + acc1.w * we1.w;
    float q1 = acc1.x * we2.x + acc1.y * we2.y + acc1.z * we2.z + acc1.w * we2.w;
#pragma unroll
    for (int o = 16; o > 0; o >>= 1) {
        p0 += __shfl_down(p0, o, 32);
        q0 += __shfl_down(q0, o, 32);
        p1 += __shfl_down(p1, o, 32);
        q1 += __shfl_down(q1, o, 32);
    }
    if (jg == 0) {
        a[row0 + r0] = p0; b[row0 + r0] = q0;
        a[row0 + r1] = p1; b[row0 + r1] = q1;
    }
}

// ---- per-row sparsemax + topK (R2: round-0 assembly, simplified write path) ----
// (1) zero-prefill the output row at kernel entry: stores have no dependencies,
//     overlap all compute; __syncthreads before the tail drains vmcnt -> the
//     sparse overwrite is WAW-safe (same CU -> same L2 serializes same-line stores).
// (2) dup detection fused into the O(m^2) rank loop (broadcast LDS reads) --
//     hash table, its init, and the CAS phase deleted. LDS 10KB -> 2.3KB.
// (3) tail = sparse overwrite of survivors only; bitmap/nibble/hval pass deleted.
__global__ __launch_bounds__(256) void k_rows(const int* __restrict__ cnt,
                                              const ushort_t* __restrict__ ecol,
                                              const float* __restrict__ a,
                                              const float* __restrict__ b,
                                              const float* __restrict__ be,
                                              float* __restrict__ adj) {
    __shared__ float zs[CAP];
    __shared__ int   cols[CAP];
    __shared__ float srt[CAP];
    __shared__ unsigned char dupf[CAP];
    __shared__ unsigned char dupsrt[CAP];
    __shared__ float s_tau, s_thresh;

    int r = blockIdx.x;
    int t = threadIdx.x;

    // stream zeros for the full output row immediately
    {
        float4 z4 = make_float4(0.f, 0.f, 0.f, 0.f);
        float4* row4 = (float4*)(adj + (size_t)r * N_);
#pragma unroll
        for (int k2 = 0; k2 < 8; ++k2) row4[t + 256 * k2] = z4;
    }

    int m = cnt[r];
    if (m > CAP) m = CAP;
    float ab = a[r] + be[0];
    for (int i = t; i < m; i += 256) {
        int c = (int)ecol[r * CAP + i];
        cols[i] = c;
        zs[i] = ab + b[c];
    }
    __syncthreads();

    if (m > 0) {
        // O(m^2) rank sort + fused first-occurrence dup detection.
        // zs[jj]/cols[jj] are wave-broadcast LDS reads (all lanes same jj): conflict-free.
        for (int i = t; i < m; i += 256) {
            float zi = zs[i];
            int ci = cols[i];
            int rank = 0;
            int dup = 0;
            for (int jj = 0; jj < m; ++jj) {
                float zj = zs[jj];
                rank += (zj > zi) || (zj == zi && jj < i);
                dup |= (jj < i) & (cols[jj] == ci);
            }
            srt[rank] = zi;
            dupsrt[rank] = (unsigned char)dup;
            dupf[i] = (unsigned char)dup;
        }
        __syncthreads();

        // wave 0: sparsemax tau (over ALL entries incl. dups, matching reference)
        // + top-K threshold (KTOP-th among first-occurrence entries)
        if (t < 64) {
            int lane = t;
            float v0 = (lane       < m) ? srt[lane]       : 0.f;
            float v1 = (lane + 64  < m) ? srt[lane + 64]  : 0.f;
            float v2 = (lane + 128 < m) ? srt[lane + 128] : 0.f;
            bool  d0 = (lane       < m) ? (dupsrt[lane]       != 0) : false;
            bool  d1 = (lane + 64  < m) ? (dupsrt[lane + 64]  != 0) : false;
            bool  d2 = (lane + 128 < m) ? (dupsrt[lane + 128] != 0) : false;

            float sc0 = v0, sc1 = v1, sc2 = v2;
#pragma unroll
            for (int o = 1; o < 64; o <<= 1) {
                float u0 = __shfl_up(sc0, o);
                float u1 = __shfl_up(sc1, o);
                float u2 = __shfl_up(sc2, o);
                if (lane >= o) { sc0 += u0; sc1 += u1; sc2 += u2; }
            }
            float tot0 = __shfl(sc0, 63);
            sc1 += tot0;
            float tot1 = __shfl(sc1, 63);
            sc2 += tot1;

            bool k0 = (lane       < m) && (1.f + (float)(lane + 1)   * v0 > sc0);
            bool k1 = (lane + 64  < m) && (1.f + (float)(lane + 65)  * v1 > sc1);
            bool k2 = (lane + 128 < m) && (1.f + (float)(lane + 129) * v2 > sc2);
            unsigned long long kb0 = __ballot(k0), kb1 = __ballot(k1), kb2 = __ballot(k2);
            int kmax;
            if (kb2)      kmax = 128 + 63 - (int)__builtin_clzll(kb2) + 1;
            else if (kb1) kmax = 64  + 63 - (int)__builtin_clzll(kb1) + 1;
            else          kmax =       63 - (int)__builtin_clzll(kb0) + 1;
            int ki = kmax - 1, ks = ki >> 6, kl = ki & 63;
            float csk = (ks == 0) ? __shfl(sc0, kl) : (ks == 1) ? __shfl(sc1, kl) : __shfl(sc2, kl);
            float tau = (csk - 1.f) / (float)kmax;

            unsigned long long dm0 = __ballot(d0), dm1 = __ballot(d1), dm2 = __ballot(d2);
            unsigned long long below = (1ull << lane) - 1ull;
            int pc0 = (int)__popcll(dm0 & below);
            int pc1 = (int)__popcll(dm0) + (int)__popcll(dm1 & below);
            int pc2 = (int)__popcll(dm0) + (int)__popcll(dm1) + (int)__popcll(dm2 & below);
            float cand = 0.f;
            if (lane       < m && !d0 && (lane       - pc0) == KTOP - 1) cand = fmaxf(cand, fmaxf(v0 - tau, 0.f));
            if (lane + 64  < m && !d1 && (lane + 64  - pc1) == KTOP - 1) cand = fmaxf(cand, fmaxf(v1 - tau, 0.f));
            if (lane + 128 < m && !d2 && (lane + 128 - pc2) == KTOP - 1) cand = fmaxf(cand, fmaxf(v2 - tau, 0.f));
#pragma unroll
            for (int o = 32; o > 0; o >>= 1) cand = fmaxf(cand, __shfl_down(cand, o));
            if (lane == 0) { s_tau = tau; s_thresh = cand; }
        }
        __syncthreads();   // drains vmcnt incl. the zero-prefill stores -> WAW-safe below
        float tau = s_tau;
        float thresh = s_thresh;

        // sparse overwrite: survivors only. Dup cols carry identical z -> identical s,
        // so excluding dups matches the reference's last-write-wins .set().
        for (int i = t; i < m; i += 256) {
            if (dupf[i]) continue;
            float s = zs[i] - tau;
            if (s > 0.f && s >= thresh) adj[(size_t)r * N_ + cols[i]] = s;
        }
    }
}

extern "C" void kernel_launch(void* const* d_in, const int* in_sizes, int n_in,
                              void* d_out, int out_size, void* d_ws, size_t ws_size,
                              hipStream_t stream) {
    const float* x  = (const float*)d_in[0];
    const int*   ei = (const int*)d_in[1];
    const float* W1 = (const float*)d_in[2];
    const float* b1 = (const float*)d_in[3];
    const float* We = (const float*)d_in[4];
    const float* be = (const float*)d_in[5];

    float* h_out   = (float*)d_out;                 // (N, NHID)
    float* adj_out = h_out + (size_t)N_ * NHID_;    // (N, N)

    float*    a    = (float*)d_ws;                  // N f32
    float*    b    = a + N_;                        // N f32
    int*      cnt  = (int*)(b + N_);                // N i32
    ushort_t* ecol = (ushort_t*)(cnt + N_);         // N*CAP u16  (~2.7 MB total ws)

    (void)hipMemsetAsync(cnt, 0, N_ * sizeof(int), stream);
    k_fused<<<512, 256, 0, stream>>>(x, ei, W1, b1, We, h_out, a, b, cnt, ecol);
    k_rows <<<N_, 256, 0, stream>>>(cnt, ecol, a, b, be, adj_out);
}

// Round 3
// 343.660 us; speedup vs baseline: 1.1195x; 1.0081x over previous
//
#include <hip/hip_runtime.h>

#define N_    8192
#define FIN_  256
#define NHID_ 128
#define E_    524288
#define KTOP  32
#define CAP   160    // bucket capacity per row; Binomial(E,1/N): mean 64, sigma 8 -> 160 = +12 sigma

typedef unsigned short ushort_t;

// ---- fused: edge scatter + h = relu(x @ W1 + b1) + a,b epilogue
//      + adj dense-zero stream (R3) ----
// 512 blocks (2/CU). Each block additionally zero-streams its 512KB slice of adj,
// interleaved with the GEMM k-loop in 4 chunks: the dependency-free stores drain
// on HBM while VALU does FMAs and L2 serves W1 -> GEMM hides under the write floor.
__global__ __launch_bounds__(256) void k_fused(const float* __restrict__ x,
                                               const int* __restrict__ ei,
                                               const float* __restrict__ W1,
                                               const float* __restrict__ b1,
                                               const float* __restrict__ We,
                                               float* __restrict__ h,
                                               float* __restrict__ a,
                                               float* __restrict__ b,
                                               int* __restrict__ cnt,
                                               ushort_t* __restrict__ ecol,
                                               float* __restrict__ adj) {
    __shared__ float xs[16][FIN_];
    int t = threadIdx.x;
    int blk = blockIdx.x;

    {
        int4 r4 = ((const int4*)ei)[blk * 256 + t];
        int4 c4 = ((const int4*)(ei + E_))[blk * 256 + t];
        int p;
        p = atomicAdd(&cnt[r4.x], 1); if (p < CAP) ecol[r4.x * CAP + p] = (ushort_t)c4.x;
        p = atomicAdd(&cnt[r4.y], 1); if (p < CAP) ecol[r4.y * CAP + p] = (ushort_t)c4.y;
        p = atomicAdd(&cnt[r4.z], 1); if (p < CAP) ecol[r4.z * CAP + p] = (ushort_t)c4.z;
        p = atomicAdd(&cnt[r4.w], 1); if (p < CAP) ecol[r4.w * CAP + p] = (ushort_t)c4.w;
    }

    int row0 = blk * 16;
    const float4* xg = (const float4*)(x + (size_t)row0 * FIN_);
    float4* xs4 = (float4*)&xs[0][0];
#pragma unroll
    for (int i = 0; i < 4; ++i) xs4[t + 256 * i] = xg[t + 256 * i];
    __syncthreads();

    int rg = t >> 5;
    int jg = t & 31;
    int r0 = 2 * rg, r1 = 2 * rg + 1;
    const float* wp = W1 + jg * 4;
    float4 bb = *(const float4*)(b1 + jg * 4);
    float4 acc0 = bb, acc1 = bb;
    const float* xr0 = xs[r0];
    const float* xr1 = xs[r1];

    // this block's 512KB zero slice of adj: 32768 float4, 128 per thread
    float4* zb = (float4*)adj + (size_t)blk * 32768 + t;
    float4 z4 = make_float4(0.f, 0.f, 0.f, 0.f);

#pragma unroll
    for (int chunk = 0; chunk < 4; ++chunk) {
        // 32 dependency-free dense-zero stores (coalesced across the block)
#pragma unroll
        for (int s = 0; s < 32; ++s) zb[(chunk * 32 + s) * 256] = z4;
        // 64 GEMM k-steps
        int kbase = chunk * 64;
#pragma unroll 8
        for (int kk = 0; kk < 64; ++kk) {
            int k = kbase + kk;
            float4 w = *(const float4*)(wp + (size_t)k * NHID_);
            float x0 = xr0[k], x1 = xr1[k];
            acc0.x = fmaf(x0, w.x, acc0.x);
            acc0.y = fmaf(x0, w.y, acc0.y);
            acc0.z = fmaf(x0, w.z, acc0.z);
            acc0.w = fmaf(x0, w.w, acc0.w);
            acc1.x = fmaf(x1, w.x, acc1.x);
            acc1.y = fmaf(x1, w.y, acc1.y);
            acc1.z = fmaf(x1, w.z, acc1.z);
            acc1.w = fmaf(x1, w.w, acc1.w);
        }
    }
    acc0.x = fmaxf(acc0.x, 0.f); acc0.y = fmaxf(acc0.y, 0.f);
    acc0.z = fmaxf(acc0.z, 0.f); acc0.w = fmaxf(acc0.w, 0.f);
    acc1.x = fmaxf(acc1.x, 0.f); acc1.y = fmaxf(acc1.y, 0.f);
    acc1.z = fmaxf(acc1.z, 0.f); acc1.w = fmaxf(acc1.w, 0.f);
    *(float4*)(h + (size_t)(row0 + r0) * NHID_ + jg * 4) = acc0;
    *(float4*)(h + (size_t)(row0 + r1) * NHID_ + jg * 4) = acc1;

    float4 we1 = *(const float4*)(We + jg * 4);
    float4 we2 = *(const float4*)(We + NHID_ + jg * 4);
    float p0 = acc0.x * we1.x + acc0.y * we1.y + acc0.z * we1.z + acc0.w * we1.w;
    float q0 = acc0.x * we2.x + acc0.y * we2.y + acc0.z * we2.z + acc0.w * we2.w;
    float p1 = acc1.x * we1.x + acc1.y * we1.y + acc1.z * we1.z + acc1.w * we1.w;
    float q1 = acc1.x * we2.x + acc1.y * we2.y + acc1.z * we2.z + acc1.w * we2.w;
#pragma unroll
    for (int o = 16; o > 0; o >>= 1) {
        p0 += __shfl_down(p0, o, 32);
        q0 += __shfl_down(q0, o, 32);
        p1 += __shfl_down(p1, o, 32);
        q1 += __shfl_down(q1, o, 32);
    }
    if (jg == 0) {
        a[row0 + r0] = p0; b[row0 + r0] = q0;
        a[row0 + r1] = p1; b[row0 + r1] = q1;
    }
}

// ---- per-row sparsemax + topK (R3: single-wave blocks, sparse-only writes) ----
// adj is already zeroed by k_fused (kernel-order WAW). Each block = ONE 64-lane
// wave (wave 0 did all post-load work before; 3 idle waves deleted). tau/kmax are
// wave-uniform from ballot/shfl; thresh broadcast via shfl -> no s_tau/s_thresh.
// 8192 one-wave blocks ~ 32/CU co-resident -> fully latency-hidden.
__global__ __launch_bounds__(64) void k_rows(const int* __restrict__ cnt,
                                             const ushort_t* __restrict__ ecol,
                                             const float* __restrict__ a,
                                             const float* __restrict__ b,
                                             const float* __restrict__ be,
                                             float* __restrict__ adj) {
    __shared__ float zs[CAP];
    __shared__ int   cols[CAP];
    __shared__ float srt[CAP];
    __shared__ unsigned char dupf[CAP];
    __shared__ unsigned char dupsrt[CAP];

    int r = blockIdx.x;
    int t = threadIdx.x;   // 0..63 (one wave)

    int m = cnt[r];
    if (m > CAP) m = CAP;
    if (m <= 0) return;

    float ab = a[r] + be[0];
    for (int i = t; i < m; i += 64) {
        int c = (int)ecol[r * CAP + i];
        cols[i] = c;
        zs[i] = ab + b[c];
    }
    __syncthreads();

    // O(m^2) rank + fused first-occurrence dup detect (broadcast LDS reads)
    for (int i = t; i < m; i += 64) {
        float zi = zs[i];
        int ci = cols[i];
        int rank = 0;
        int dup = 0;
        for (int jj = 0; jj < m; ++jj) {
            float zj = zs[jj];
            rank += (zj > zi) || (zj == zi && jj < i);
            dup |= (jj < i) & (cols[jj] == ci);
        }
        srt[rank] = zi;
        dupsrt[rank] = (unsigned char)dup;
        dupf[i] = (unsigned char)dup;
    }
    __syncthreads();

    int lane = t;
    float v0 = (lane       < m) ? srt[lane]       : 0.f;
    float v1 = (lane + 64  < m) ? srt[lane + 64]  : 0.f;
    float v2 = (lane + 128 < m) ? srt[lane + 128] : 0.f;
    bool  d0 = (lane       < m) ? (dupsrt[lane]       != 0) : false;
    bool  d1 = (lane + 64  < m) ? (dupsrt[lane + 64]  != 0) : false;
    bool  d2 = (lane + 128 < m) ? (dupsrt[lane + 128] != 0) : false;

    float sc0 = v0, sc1 = v1, sc2 = v2;
#pragma unroll
    for (int o = 1; o < 64; o <<= 1) {
        float u0 = __shfl_up(sc0, o);
        float u1 = __shfl_up(sc1, o);
        float u2 = __shfl_up(sc2, o);
        if (lane >= o) { sc0 += u0; sc1 += u1; sc2 += u2; }
    }
    float tot0 = __shfl(sc0, 63);
    sc1 += tot0;
    float tot1 = __shfl(sc1, 63);
    sc2 += tot1;

    bool k0 = (lane       < m) && (1.f + (float)(lane + 1)   * v0 > sc0);
    bool k1 = (lane + 64  < m) && (1.f + (float)(lane + 65)  * v1 > sc1);
    bool k2 = (lane + 128 < m) && (1.f + (float)(lane + 129) * v2 > sc2);
    unsigned long long kb0 = __ballot(k0), kb1 = __ballot(k1), kb2 = __ballot(k2);
    int kmax;
    if (kb2)      kmax = 128 + 63 - (int)__builtin_clzll(kb2) + 1;
    else if (kb1) kmax = 64  + 63 - (int)__builtin_clzll(kb1) + 1;
    else          kmax =       63 - (int)__builtin_clzll(kb0) + 1;
    int ki = kmax - 1, ks = ki >> 6, kl = ki & 63;
    float csk = (ks == 0) ? __shfl(sc0, kl) : (ks == 1) ? __shfl(sc1, kl) : __shfl(sc2, kl);
    float tau = (csk - 1.f) / (float)kmax;    // wave-uniform

    unsigned long long dm0 = __ballot(d0), dm1 = __ballot(d1), dm2 = __ballot(d2);
    unsigned long long below = (1ull << lane) - 1ull;
    int pc0 = (int)__popcll(dm0 & below);
    int pc1 = (int)__popcll(dm0) + (int)__popcll(dm1 & below);
    int pc2 = (int)__popcll(dm0) + (int)__popcll(dm1) + (int)__popcll(dm2 & below);
    float cand = 0.f;
    if (lane       < m && !d0 && (lane       - pc0) == KTOP - 1) cand = fmaxf(cand, fmaxf(v0 - tau, 0.f));
    if (lane + 64  < m && !d1 && (lane + 64  - pc1) == KTOP - 1) cand = fmaxf(cand, fmaxf(v1 - tau, 0.f));
    if (lane + 128 < m && !d2 && (lane + 128 - pc2) == KTOP - 1) cand = fmaxf(cand, fmaxf(v2 - tau, 0.f));
#pragma unroll
    for (int o = 32; o > 0; o >>= 1) cand = fmaxf(cand, __shfl_down(cand, o));
    float thresh = __shfl(cand, 0);           // broadcast to all lanes

    // sparse overwrite of pre-zeroed adj: survivors only. Dup cols carry identical
    // z -> identical s, so excluding dups matches the reference's .set().
    for (int i = t; i < m; i += 64) {
        if (dupf[i]) continue;
        float s = zs[i] - tau;
        if (s > 0.f && s >= thresh) adj[(size_t)r * N_ + cols[i]] = s;
    }
}

extern "C" void kernel_launch(void* const* d_in, const int* in_sizes, int n_in,
                              void* d_out, int out_size, void* d_ws, size_t ws_size,
                              hipStream_t stream) {
    const float* x  = (const float*)d_in[0];
    const int*   ei = (const int*)d_in[1];
    const float* W1 = (const float*)d_in[2];
    const float* b1 = (const float*)d_in[3];
    const float* We = (const float*)d_in[4];
    const float* be = (const float*)d_in[5];

    float* h_out   = (float*)d_out;                 // (N, NHID)
    float* adj_out = h_out + (size_t)N_ * NHID_;    // (N, N)

    float*    a    = (float*)d_ws;                  // N f32
    float*    b    = a + N_;                        // N f32
    int*      cnt  = (int*)(b + N_);                // N i32
    ushort_t* ecol = (ushort_t*)(cnt + N_);         // N*CAP u16  (~2.7 MB total ws)

    (void)hipMemsetAsync(cnt, 0, N_ * sizeof(int), stream);
    k_fused<<<512, 256, 0, stream>>>(x, ei, W1, b1, We, h_out, a, b, cnt, ecol, adj_out);
    k_rows <<<N_, 64, 0, stream>>>(cnt, ecol, a, b, be, adj_out);
}